// Round 9
// baseline (1892.756 us; speedup 1.0000x reference)
//
#include <hip/hip_runtime.h>
#include <stdint.h>

#define BATCH 16
#define NPTS  4096
#define NSAMP 1024

typedef __attribute__((ext_vector_type(8))) short  short8;
typedef __attribute__((ext_vector_type(4))) float  floatx4;

__device__ __forceinline__ unsigned short f2bf(float f) {
    unsigned u = __float_as_uint(f);
    unsigned r = (u + 0x7FFFu + ((u >> 16) & 1u)) >> 16;
    return (unsigned short)r;
}

// u64 max with DPP row-rotate source (intra-16-lane), VALU-latency path.
template<int CTRL>
__device__ __forceinline__ uint64_t dpp_max_u64(uint64_t k) {
    int lo = (int)(unsigned)k;
    int hi = (int)(unsigned)(k >> 32);
    int lo2 = __builtin_amdgcn_update_dpp(0, lo, CTRL, 0xF, 0xF, false);
    int hi2 = __builtin_amdgcn_update_dpp(0, hi, CTRL, 0xF, 0xF, false);
    uint64_t o = ((uint64_t)(unsigned)hi2 << 32) | (unsigned)lo2;
    return o > k ? o : k;
}

// (key, xyz) tuple max via DPP — coords ride along with the winning key.
template<int CTRL>
__device__ __forceinline__ void dpp_max_cand(uint64_t& k, float& x, float& y, float& z) {
    int lo = (int)(unsigned)k, hi = (int)(unsigned)(k >> 32);
    int lo2 = __builtin_amdgcn_update_dpp(0, lo, CTRL, 0xF, 0xF, false);
    int hi2 = __builtin_amdgcn_update_dpp(0, hi, CTRL, 0xF, 0xF, false);
    int xi  = __builtin_amdgcn_update_dpp(0, __float_as_int(x), CTRL, 0xF, 0xF, false);
    int yi  = __builtin_amdgcn_update_dpp(0, __float_as_int(y), CTRL, 0xF, 0xF, false);
    int zi  = __builtin_amdgcn_update_dpp(0, __float_as_int(z), CTRL, 0xF, 0xF, false);
    uint64_t ok = ((uint64_t)(unsigned)hi2 << 32) | (unsigned)lo2;
    bool take = ok > k;
    k = take ? ok : k;
    x = take ? __int_as_float(xi) : x;
    y = take ? __int_as_float(yi) : y;
    z = take ? __int_as_float(zi) : z;
}

// ---------------------------------------------------------------------------
// FPS: one block per batch, 512 threads. Bit-exact numpy semantics:
// d = dx*dx + dy*dy + dz*dz (no FMA), dist=min, argmax first-index
// tie-break via packed u64 (dist_bits<<32)|~idx max (max over distinct keys
// is order-independent). Wave winners publish (key, coords) pre-barrier;
// post-barrier tail is 2 LDS reads + 3 DPP tuple stages — no index gather.
// ---------------------------------------------------------------------------
__global__ __launch_bounds__(512) void fps_kernel(
    const float* __restrict__ xyz,            // [B,N,3] f32
    float* __restrict__ out_xyz)              // d_out head [B,S,3] f32
{
#pragma clang fp contract(off)
    const int b    = blockIdx.x;
    const int tid  = threadIdx.x;
    const int lane = tid & 63;
    const int wave = tid >> 6;                // 0..7
    const float* xb = xyz + (size_t)b * NPTS * 3;

    __shared__ __align__(16) float4 xyzsh[NPTS];   // 64 KB packed coords
    __shared__ float cents[NSAMP * 3];
    __shared__ uint64_t kq[2][8];
    __shared__ __align__(16) float4 cq[2][8];

    float px[8], py[8], pz[8], dist[8];
#pragma unroll
    for (int i = 0; i < 8; ++i) {
        int p = tid + (i << 9);
        px[i] = xb[p*3+0];
        py[i] = xb[p*3+1];
        pz[i] = xb[p*3+2];
        dist[i] = 1e10f;
        xyzsh[p] = make_float4(px[i], py[i], pz[i], 0.f);
    }
    __syncthreads();

    float cx = xb[0], cy = xb[1], cz = xb[2];

    for (int it = 0; it < NSAMP; ++it) {
        if (tid == 0) {                       // LDS only — no vmcnt traffic
            cents[it*3+0] = cx; cents[it*3+1] = cy; cents[it*3+2] = cz;
        }
        if (it == NSAMP - 1) break;

        // ---- update dists (exact ref op order) ----
#pragma unroll
        for (int i = 0; i < 8; ++i) {
            float dx = px[i] - cx, dy = py[i] - cy, dz = pz[i] - cz;
            float d = dx*dx; d = d + dy*dy; d = d + dz*dz;
            dist[i] = fminf(dist[i], d);
        }
        // ---- thread-local max (exact) + lowest-slot equality scan ----
        float m4[4], m2[2];
#pragma unroll
        for (int i = 0; i < 4; ++i) m4[i] = fmaxf(dist[2*i], dist[2*i+1]);
        m2[0] = fmaxf(m4[0], m4[1]); m2[1] = fmaxf(m4[2], m4[3]);
        float tmax = fmaxf(m2[0], m2[1]);
        int slot = 7;
#pragma unroll
        for (int i = 6; i >= 0; --i) slot = (dist[i] == tmax) ? i : slot;
        unsigned idx = (unsigned)(tid + (slot << 9));
        uint64_t k = ((uint64_t)__float_as_uint(tmax) << 32) | (~idx);

        // ---- wave reduce: DPP within 16 lanes, xor16 swizzle, readlane ----
        k = dpp_max_u64<0x121>(k);   // row_ror:1
        k = dpp_max_u64<0x122>(k);   // row_ror:2
        k = dpp_max_u64<0x124>(k);   // row_ror:4
        k = dpp_max_u64<0x128>(k);   // row_ror:8  -> row(16) all-reduce
        {
            int lo = (int)(unsigned)k, hi = (int)(unsigned)(k >> 32);
            int lo2 = __builtin_amdgcn_ds_swizzle(lo, 0x401F);  // xor 16
            int hi2 = __builtin_amdgcn_ds_swizzle(hi, 0x401F);
            uint64_t o = ((uint64_t)(unsigned)hi2 << 32) | (unsigned)lo2;
            k = o > k ? o : k;
        }
        unsigned klo = (unsigned)k, khi = (unsigned)(k >> 32);
        uint64_t kA = ((uint64_t)(unsigned)__builtin_amdgcn_readlane((int)khi, 0)  << 32)
                    |            (unsigned)__builtin_amdgcn_readlane((int)klo, 0);
        uint64_t kB = ((uint64_t)(unsigned)__builtin_amdgcn_readlane((int)khi, 32) << 32)
                    |            (unsigned)__builtin_amdgcn_readlane((int)klo, 32);
        uint64_t wk = kA > kB ? kA : kB;

        // ---- publish wave winner (key + coords) pre-barrier ----
        int pb = it & 1;
        if (lane == 0) {
            int curw = (int)~((unsigned)wk);
            float4 c = xyzsh[curw];
            kq[pb][wave] = wk;
            cq[pb][wave] = c;
        }
        __syncthreads();                      // only lgkm pending — cheap

        // ---- cross-wave: 8-periodic broadcast + 3 DPP tuple stages ----
        uint64_t gk = kq[pb][lane & 7];
        float4  gc = cq[pb][lane & 7];
        float gx = gc.x, gy = gc.y, gz = gc.z;
        dpp_max_cand<0x121>(gk, gx, gy, gz);  // ror1 (mod-8 periodic data)
        dpp_max_cand<0x122>(gk, gx, gy, gz);  // ror2
        dpp_max_cand<0x124>(gk, gx, gy, gz);  // ror4 -> all-8 winner
        cx = gx; cy = gy; cz = gz;
    }

    __syncthreads();
    for (int i = tid; i < NSAMP*3; i += 512)  // coalesced bulk store
        out_xyz[(size_t)b*NSAMP*3 + i] = cents[i];
}

// ---------------------------------------------------------------------------
// feat f32 -> bf16 table (one-shot; phases then stage with pure u16 copies)
// ---------------------------------------------------------------------------
__global__ __launch_bounds__(256) void conv_feat_kernel(
    const float* __restrict__ feat, unsigned short* __restrict__ featb)
{
    int t = blockIdx.x * 256 + threadIdx.x;   // 8 elems each; 4.19M total
    const float4* fp = (const float4*)feat + (size_t)t*2;
    float4 a = fp[0], c = fp[1];
    uint4 o;
    o.x = (unsigned)f2bf(a.x) | ((unsigned)f2bf(a.y) << 16);
    o.y = (unsigned)f2bf(a.z) | ((unsigned)f2bf(a.w) << 16);
    o.z = (unsigned)f2bf(c.x) | ((unsigned)f2bf(c.y) << 16);
    o.w = (unsigned)f2bf(c.z) | ((unsigned)f2bf(c.w) << 16);
    ((uint4*)featb)[t] = o;
}

// ---------------------------------------------------------------------------
// KNN: one wave per query. Filter-then-merge top-64 on packed u64
// (key<<32|idx) — exact lax.top_k semantics.
// ---------------------------------------------------------------------------
__global__ __launch_bounds__(256) void knn_kernel(
    const float* __restrict__ xyz,
    const float* __restrict__ new_xyz,        // Output 0 (f32)
    unsigned short* __restrict__ knn_idx)     // [B*S, 64]
{
#pragma clang fp contract(off)
    __shared__ float xs[NPTS], ys[NPTS], zs[NPTS];
    __shared__ uint64_t buf[4][64];
    const int tid  = threadIdx.x;
    const int lane = tid & 63;
    const int wave = tid >> 6;
    const int q = blockIdx.x * 4 + wave;
    const int b = q >> 10;
    const float* xb = xyz + (size_t)b * NPTS * 3;

    for (int i = tid; i < NPTS; i += 256) {
        xs[i] = xb[i*3+0];
        ys[i] = xb[i*3+1];
        zs[i] = xb[i*3+2];
    }
    __syncthreads();

    const float qx = new_xyz[q*3+0], qy = new_xyz[q*3+1], qz = new_xyz[q*3+2];
    float aa = qx*qx; aa = aa + qy*qy; aa = aa + qz*qz;

    auto keyof = [&](int c) -> unsigned {
        float x = xs[c], y = ys[c], z = zs[c];
        float bb = x*x;  bb = bb + y*y;   bb = bb + z*z;
        float dt = qx*x; dt = dt + qy*y;  dt = dt + qz*z;
        float d2 = (aa + bb) - 2.0f*dt;
        unsigned u = __float_as_uint(d2);
        return (u & 0x80000000u) ? ~u : (u | 0x80000000u);
    };
    auto shfl64 = [&](uint64_t v, int src) -> uint64_t {
        int lo = __shfl((int)(unsigned)v, src);
        int hi = __shfl((int)(unsigned)(v >> 32), src);
        return ((uint64_t)(unsigned)hi << 32) | (unsigned)lo;
    };
    auto shflx64 = [&](uint64_t v, int m) -> uint64_t {
        int lo = __shfl_xor((int)(unsigned)v, m);
        int hi = __shfl_xor((int)(unsigned)(v >> 32), m);
        return ((uint64_t)(unsigned)hi << 32) | (unsigned)lo;
    };
    auto sortP = [&](uint64_t &p) {        // ascending bitonic sort across 64
#pragma unroll
        for (int kk = 2; kk <= 64; kk <<= 1) {
#pragma unroll
            for (int j = kk >> 1; j >= 1; j >>= 1) {
                uint64_t o = shflx64(p, j);
                bool up    = ((lane & kk) == 0);
                bool lower = ((lane & j) == 0);
                bool oless = o < p;
                bool keep  = (up == lower) ? oless : !oless;
                if (keep) p = o;
            }
        }
    };
    auto mergeP = [&](uint64_t &P, uint64_t Bv) {  // both asc; keep 64 smallest
        uint64_t rev = shfl64(Bv, 63 - lane);
        if (rev < P) P = rev;                      // bitonic now
#pragma unroll
        for (int j = 32; j >= 1; j >>= 1) {
            uint64_t o = shflx64(P, j);
            bool lower = ((lane & j) == 0);
            bool oless = o < P;
            bool keep  = lower ? oless : !oless;
            if (keep) P = o;
        }
    };

    uint64_t P = ((uint64_t)keyof(lane) << 32) | (unsigned)lane;
    sortP(P);
    uint64_t Pmax = shfl64(P, 63);
    int cnt = 0;                                   // wave-uniform buffer fill

    for (int bt = 1; bt < 64; ++bt) {
        int c = (bt << 6) + lane;
        uint64_t cand = ((uint64_t)keyof(c) << 32) | (unsigned)c;
        bool qual = cand < Pmax;
        unsigned long long mask = __ballot(qual);
        if (mask == 0ull) continue;
        int n = __popcll(mask);
        if (cnt + n > 64) {                        // flush buffer
            uint64_t Bv = (lane < cnt) ? buf[wave][lane] : ~0ull;
            sortP(Bv);
            mergeP(P, Bv);
            Pmax = shfl64(P, 63);
            cnt = 0;
            qual = qual && (cand < Pmax);          // re-qualify (tightened)
            mask = __ballot(qual);
            n = __popcll(mask);
        }
        if (qual) {
            int pos = cnt + __popcll(mask & ((1ull << lane) - 1ull));
            buf[wave][pos] = cand;
        }
        cnt += n;
    }
    if (cnt > 0) {
        uint64_t Bv = (lane < cnt) ? buf[wave][lane] : ~0ull;
        sortP(Bv);
        mergeP(P, Bv);
    }
    knn_idx[(size_t)q*64 + lane] = (unsigned short)(P & 0xFFFFu);
}

// ---------------------------------------------------------------------------
// MLP phases — all 3 scales in one dispatch (3584 blocks, 8 groups/block).
// staged=1: feats come from pre-converted bf16 table (pure u16 copies).
// a_lds transpose slabs are WAVE-PRIVATE (wave w touches rows w*16..w*16+15
// only) and LDS completes in order per wave -> no barriers around the
// transpose round-trips. Barriers kept: after staging (cross-wave g_lds),
// before writeback (cross-wave wavemax).
// ---------------------------------------------------------------------------
#define GPB 8   // groups per block

template<int PHASE>
__global__ __launch_bounds__(256) void mlp_phase(
    const float* __restrict__ xyz,
    const float* __restrict__ feat,
    const float* __restrict__ w0,
    const float* __restrict__ w1,
    const float* __restrict__ w2,
    const float* __restrict__ new_xyz,    // Output 0 (f32)
    const unsigned short* __restrict__ knn,
    const unsigned short* __restrict__ featb,  // staged bf16 feats (or null)
    int staged,
    const float* __restrict__ bnp,        // [3][3][128][2] (s,t)
    float* __restrict__ stats,            // [3][3][128][2] (sum,sumsq)
    float* __restrict__ out1)             // fused region [B*S, 384] f32
{
    __shared__ __align__(16) unsigned short g_lds[64*104];
    __shared__ __align__(16) unsigned short a_lds[64*72];
    __shared__ float stat_lds[256];
    __shared__ float wavemax[4*128];

    const int tid  = threadIdx.x;
    const int lane = tid & 63;
    const int wave = tid >> 6;
    const int n16  = lane & 15;
    const int quad = lane >> 4;

    int scale, g0;
    {
        int blk = blockIdx.x;
        if (blk < 512)       { scale = 0; g0 = blk * GPB; }
        else if (blk < 1536) { scale = 1; g0 = (blk - 512) * GPB; }
        else                 { scale = 2; g0 = (blk - 1536) * GPB; }
    }
    const int KNB = 16 << scale;
    const int cpg = 4 >> scale;           // centroids per 64-row group
    const int wpc = 1 << scale;           // waves per centroid

    // ---- W fragments (B-operand layout: n=lane&15, k=quad*8+j) ----
    short8 w1f[4][3];
#pragma unroll
    for (int nt = 0; nt < 4; ++nt)
#pragma unroll
        for (int kb = 0; kb < 3; ++kb) {
            short8 f;
#pragma unroll
            for (int j = 0; j < 8; ++j) {
                int kg = kb*32 + quad*8 + j;
                int n  = nt*16 + n16;
                unsigned short v = 0;
                if (kg < 67) {
                    int ci = (kg < 64) ? (kg + 3) : (kg - 64);
                    v = f2bf(w0[(size_t)(scale*64 + n)*67 + ci]);
                }
                f[j] = (short)v;
            }
            w1f[nt][kb] = f;
        }
    short8 w2f[4][2];
    if constexpr (PHASE >= 2) {
#pragma unroll
        for (int nt = 0; nt < 4; ++nt)
#pragma unroll
            for (int kb = 0; kb < 2; ++kb) {
                short8 f;
#pragma unroll
                for (int j = 0; j < 8; ++j) {
                    int kg = kb*32 + quad*8 + j;
                    int n  = nt*16 + n16;
                    f[j] = (short)f2bf(w1[(size_t)(scale*64 + n)*64 + kg]);
                }
                w2f[nt][kb] = f;
            }
    }
    short8 w3f[8][2];
    if constexpr (PHASE >= 3) {
#pragma unroll
        for (int nt = 0; nt < 8; ++nt)
#pragma unroll
            for (int kb = 0; kb < 2; ++kb) {
                short8 f;
#pragma unroll
                for (int j = 0; j < 8; ++j) {
                    int kg = kb*32 + quad*8 + j;
                    int n  = nt*16 + n16;
                    f[j] = (short)f2bf(w2[(size_t)(scale*128 + n)*64 + kg]);
                }
                w3f[nt][kb] = f;
            }
    }

    float s1p[4], t1p[4], s2p[4], t2p[4];
    if constexpr (PHASE >= 2) {
#pragma unroll
        for (int nt = 0; nt < 4; ++nt) {
            int o = ((0*3 + scale)*128 + nt*16 + n16)*2;
            s1p[nt] = bnp[o]; t1p[nt] = bnp[o+1];
        }
    }
    if constexpr (PHASE >= 3) {
#pragma unroll
        for (int nt = 0; nt < 4; ++nt) {
            int o = ((1*3 + scale)*128 + nt*16 + n16)*2;
            s2p[nt] = bnp[o]; t2p[nt] = bnp[o+1];
        }
    }

    float sac[8], sqac[8];
#pragma unroll
    for (int i = 0; i < 8; ++i) { sac[i] = 0.f; sqac[i] = 0.f; }
    stat_lds[tid] = 0.f;
    __syncthreads();

    for (int g = g0; g < g0 + GPB; ++g) {
        const int cb = g * cpg;
        // ---- build g tile: 64 rows x 104 cols (bf16) ----
        {
            const int r   = tid >> 2;
            const int sub = tid & 3;
            const int ci  = cb + (r >> (4 + scale));
            const int j   = r & (KNB - 1);
            const int n   = knn[(size_t)ci*64 + j];
            const int b   = ci >> 10;
            if (staged) {
                const unsigned short* frow = featb + ((size_t)(b*NPTS + n))*64 + sub*16;
                uint4 c0 = ((const uint4*)frow)[0];
                uint4 c1 = ((const uint4*)frow)[1];
                *(uint4*)&g_lds[r*104 + sub*16]     = c0;
                *(uint4*)&g_lds[r*104 + sub*16 + 8] = c1;
            } else {
                const float* frow = feat + ((size_t)(b*NPTS + n))*64 + sub*16;
                unsigned short h[16];
#pragma unroll
                for (int u = 0; u < 16; ++u) h[u] = f2bf(frow[u]);
                uint4 p0, p1;
                p0.x = (unsigned)h[0]  | ((unsigned)h[1]  << 16);
                p0.y = (unsigned)h[2]  | ((unsigned)h[3]  << 16);
                p0.z = (unsigned)h[4]  | ((unsigned)h[5]  << 16);
                p0.w = (unsigned)h[6]  | ((unsigned)h[7]  << 16);
                p1.x = (unsigned)h[8]  | ((unsigned)h[9]  << 16);
                p1.y = (unsigned)h[10] | ((unsigned)h[11] << 16);
                p1.z = (unsigned)h[12] | ((unsigned)h[13] << 16);
                p1.w = (unsigned)h[14] | ((unsigned)h[15] << 16);
                *(uint4*)&g_lds[r*104 + sub*16]     = p0;
                *(uint4*)&g_lds[r*104 + sub*16 + 8] = p1;
            }
            if (sub == 0) {
                const float* nx = new_xyz + (size_t)ci*3;
                const float* xp = xyz + ((size_t)(b*NPTS + n))*3;
                unsigned short h0 = f2bf(xp[0] - nx[0]);
                unsigned short h1 = f2bf(xp[1] - nx[1]);
                unsigned short h2 = f2bf(xp[2] - nx[2]);
                uint4 z = make_uint4((unsigned)h0 | ((unsigned)h1 << 16),
                                     (unsigned)h2, 0u, 0u);
                *(uint4*)&g_lds[r*104 + 64] = z;
                *(uint4*)&g_lds[r*104 + 72] = make_uint4(0u,0u,0u,0u);
            } else if (sub == 1) {
                *(uint4*)&g_lds[r*104 + 80] = make_uint4(0u,0u,0u,0u);
            } else if (sub == 2) {
                *(uint4*)&g_lds[r*104 + 88] = make_uint4(0u,0u,0u,0u);
            }
        }
        __syncthreads();

        // ---- L1 ----
        const int rb = wave*16 + n16;  // A-row for this lane
        short8 a0 = *(const short8*)&g_lds[rb*104 +      quad*8];
        short8 a1 = *(const short8*)&g_lds[rb*104 + 32 + quad*8];
        short8 a2 = *(const short8*)&g_lds[rb*104 + 64 + quad*8];
        floatx4 acc[4];
#pragma unroll
        for (int nt = 0; nt < 4; ++nt) {
            floatx4 c = {0.f,0.f,0.f,0.f};
            c = __builtin_amdgcn_mfma_f32_16x16x32_bf16(a0, w1f[nt][0], c, 0,0,0);
            c = __builtin_amdgcn_mfma_f32_16x16x32_bf16(a1, w1f[nt][1], c, 0,0,0);
            c = __builtin_amdgcn_mfma_f32_16x16x32_bf16(a2, w1f[nt][2], c, 0,0,0);
            acc[nt] = c;
        }

        if constexpr (PHASE == 1) {
#pragma unroll
            for (int nt = 0; nt < 4; ++nt) {
                floatx4 c = acc[nt];
                sac[nt]  += c[0]+c[1]+c[2]+c[3];
                sqac[nt] += c[0]*c[0]+c[1]*c[1]+c[2]*c[2]+c[3]*c[3];
            }
        }
        if constexpr (PHASE >= 2) {
            // a1 = relu(affine(x1)) -> LDS transpose (wave-private slab,
            // DS in-order per wave -> no barrier needed)
#pragma unroll
            for (int nt = 0; nt < 4; ++nt) {
                int ch = nt*16 + n16;
#pragma unroll
                for (int r = 0; r < 4; ++r) {
                    float v = acc[nt][r]*s1p[nt] + t1p[nt];
                    v = fmaxf(v, 0.f);
                    a_lds[(wave*16 + quad*4 + r)*72 + ch] = f2bf(v);
                }
            }
            short8 e0 = *(const short8*)&a_lds[rb*72 +      quad*8];
            short8 e1 = *(const short8*)&a_lds[rb*72 + 32 + quad*8];
            floatx4 acc2[4];
#pragma unroll
            for (int nt = 0; nt < 4; ++nt) {
                floatx4 c = {0.f,0.f,0.f,0.f};
                c = __builtin_amdgcn_mfma_f32_16x16x32_bf16(e0, w2f[nt][0], c, 0,0,0);
                c = __builtin_amdgcn_mfma_f32_16x16x32_bf16(e1, w2f[nt][1], c, 0,0,0);
                acc2[nt] = c;
            }
            if constexpr (PHASE == 2) {
#pragma unroll
                for (int nt = 0; nt < 4; ++nt) {
                    floatx4 c = acc2[nt];
                    sac[nt]  += c[0]+c[1]+c[2]+c[3];
                    sqac[nt] += c[0]*c[0]+c[1]*c[1]+c[2]*c[2]+c[3]*c[3];
                }
            }
            if constexpr (PHASE == 3) {
#pragma unroll
                for (int nt = 0; nt < 4; ++nt) {
                    int ch = nt*16 + n16;
#pragma unroll
                    for (int r = 0; r < 4; ++r) {
                        float v = acc2[nt][r]*s2p[nt] + t2p[nt];
                        v = fmaxf(v, 0.f);
                        a_lds[(wave*16 + quad*4 + r)*72 + ch] = f2bf(v);
                    }
                }
                short8 f0 = *(const short8*)&a_lds[rb*72 +      quad*8];
                short8 f1 = *(const short8*)&a_lds[rb*72 + 32 + quad*8];
                floatx4 acc3[8];
#pragma unroll
                for (int nt = 0; nt < 8; ++nt) {
                    floatx4 c = {0.f,0.f,0.f,0.f};
                    c = __builtin_amdgcn_mfma_f32_16x16x32_bf16(f0, w3f[nt][0], c, 0,0,0);
                    c = __builtin_amdgcn_mfma_f32_16x16x32_bf16(f1, w3f[nt][1], c, 0,0,0);
                    acc3[nt] = c;
                }
#pragma unroll
                for (int nt = 0; nt < 8; ++nt) {
                    floatx4 c = acc3[nt];
                    sac[nt]  += c[0]+c[1]+c[2]+c[3];
                    sqac[nt] += c[0]*c[0]+c[1]*c[1]+c[2]*c[2]+c[3]*c[3];
                    float m = fmaxf(fmaxf(c[0],c[1]), fmaxf(c[2],c[3]));
                    m = fmaxf(m, __shfl_xor(m, 16));
                    m = fmaxf(m, __shfl_xor(m, 32));
                    if (lane < 16) wavemax[wave*128 + nt*16 + n16] = m;
                }
            }
        }
        __syncthreads();   // g_lds reuse (all) + cross-wave wavemax (PHASE 3)
        if constexpr (PHASE == 3) {
            const int ch = tid & 127;
            for (int ic = tid >> 7; ic < cpg; ic += 2) {
                float m = wavemax[(ic*wpc)*128 + ch];
                for (int w = 1; w < wpc; ++w)
                    m = fmaxf(m, wavemax[(ic*wpc + w)*128 + ch]);
                // raw (pre-BN3) max, f32, directly in the final output slot
                out1[(size_t)(cb + ic)*384 + scale*128 + ch] = m;
            }
            // no trailing barrier: next staging sync orders these reads
        }
    }

    // ---- flush stats ----
    const int NCH = (PHASE == 3) ? 8 : 4;
#pragma unroll
    for (int nt = 0; nt < 8; ++nt) {
        if (nt >= NCH) break;
        float v  = sac[nt], v2 = sqac[nt];
        v  += __shfl_xor(v, 16);  v  += __shfl_xor(v, 32);
        v2 += __shfl_xor(v2, 16); v2 += __shfl_xor(v2, 32);
        if (lane < 16) {
            int ch = nt*16 + n16;
            atomicAdd(&stat_lds[ch*2],   v);
            atomicAdd(&stat_lds[ch*2+1], v2);
        }
    }
    __syncthreads();
    const int layer = PHASE - 1;
    const int nch = (PHASE == 3) ? 128 : 64;
    if (tid < nch*2) {
        atomicAdd(&stats[(size_t)(layer*3 + scale)*256 + tid], stat_lds[tid]);
    }
}

// ---------------------------------------------------------------------------
__global__ void bn_params_kernel(
    const float* __restrict__ stats, float* __restrict__ bnp,
    const float* __restrict__ gamma, const float* __restrict__ beta,
    int layer, int nch)
{
    int t = blockIdx.x * blockDim.x + threadIdx.x;
    if (t >= 3*nch) return;
    int scale = t / nch, ch = t % nch;
    float M = 16384.0f * (float)(16 << scale);
    int o = ((layer*3 + scale)*128 + ch)*2;
    float sum = stats[o], sumsq = stats[o+1];
    float mean = sum / M;
    float var = sumsq / M - mean*mean;
    var = fmaxf(var, 0.f);
    float ga = gamma[scale*nch + ch];
    float be = beta[scale*nch + ch];
    float s  = ga / sqrtf(var + 1e-5f);
    float tt = be - mean * s;
    bnp[o] = s; bnp[o+1] = tt;
}

// In-place elementwise BN3+ReLU over the fused output region (f32).
__global__ void finalize_kernel(
    const float* __restrict__ bnp,
    float* __restrict__ out1)   // [B*S, 384] f32, holds raw maxima
{
    int t = blockIdx.x * 256 + threadIdx.x;    // flat over 16384*384
    int q = t / 384;
    int c = t - q*384;
    int scale = c >> 7;
    int ch = c & 127;
    float m = out1[t];
    int o = ((2*3 + scale)*128 + ch)*2;
    float v = m * bnp[o] + bnp[o+1];
    v = fmaxf(v, 0.f);
    out1[t] = v;
}

// ---------------------------------------------------------------------------
extern "C" void kernel_launch(void* const* d_in, const int* in_sizes, int n_in,
                              void* d_out, int out_size, void* d_ws, size_t ws_size,
                              hipStream_t stream)
{
    (void)in_sizes; (void)n_in; (void)out_size;
    const float* xyz  = (const float*)d_in[0];
    const float* feat = (const float*)d_in[1];
    const float* w0   = (const float*)d_in[2];
    const float* w1   = (const float*)d_in[3];
    const float* w2   = (const float*)d_in[4];
    const float* g0   = (const float*)d_in[5];
    const float* g1   = (const float*)d_in[6];
    const float* g2   = (const float*)d_in[7];
    const float* b0   = (const float*)d_in[8];
    const float* b1   = (const float*)d_in[9];
    const float* b2   = (const float*)d_in[10];
    float* out  = (float*)d_out;
    float* out0 = out;                 // [B,S,3]
    float* out1 = out + 49152;         // fused [B*S,384]

    // ws layout: knn 2MB | featb 8MB | stats | bnp   (staged, NEED=10.5MB)
    //            knn 2MB | stats | bnp                (fallback)
    char* ws = (char*)d_ws;
    const size_t NEED = 2097152ull + 8388608ull + 9216ull + 9216ull;
    const int staged = (ws_size >= NEED) ? 1 : 0;
    unsigned short* knn   = (unsigned short*)(ws + 0);
    unsigned short* featb = staged ? (unsigned short*)(ws + 2097152) : nullptr;
    float* stats = (float*)(ws + (staged ? 10485760u : 2097152u));
    float* bnp   = stats + 2304;

    hipMemsetAsync(stats, 0, 9216, stream);
    fps_kernel<<<16, 512, 0, stream>>>(xyz, out0);
    if (staged) conv_feat_kernel<<<2048, 256, 0, stream>>>(feat, featb);
    knn_kernel<<<4096, 256, 0, stream>>>(xyz, out0, knn);

    mlp_phase<1><<<3584,256,0,stream>>>(xyz,feat,w0,w1,w2,out0,knn,featb,staged,bnp,stats,out1);
    bn_params_kernel<<<1,256,0,stream>>>(stats, bnp, g0, b0, 0, 64);

    mlp_phase<2><<<3584,256,0,stream>>>(xyz,feat,w0,w1,w2,out0,knn,featb,staged,bnp,stats,out1);
    bn_params_kernel<<<1,256,0,stream>>>(stats, bnp, g1, b1, 1, 64);

    mlp_phase<3><<<3584,256,0,stream>>>(xyz,feat,w0,w1,w2,out0,knn,featb,staged,bnp,stats,out1);
    bn_params_kernel<<<2,256,0,stream>>>(stats, bnp, g2, b2, 2, 128);

    finalize_kernel<<<24576, 256, 0, stream>>>(bnp, out1);
}

// Round 10
// 1687.949 us; speedup vs baseline: 1.1213x; 1.1213x over previous
//
#include <hip/hip_runtime.h>
#include <stdint.h>

#define BATCH 16
#define NPTS  4096
#define NSAMP 1024

typedef __attribute__((ext_vector_type(8))) short  short8;
typedef __attribute__((ext_vector_type(4))) float  floatx4;

__device__ __forceinline__ unsigned short f2bf(float f) {
    unsigned u = __float_as_uint(f);
    unsigned r = (u + 0x7FFFu + ((u >> 16) & 1u)) >> 16;
    return (unsigned short)r;
}

// u64 max with DPP row-rotate source (intra-16-lane), VALU-latency path.
template<int CTRL>
__device__ __forceinline__ uint64_t dpp_max_u64(uint64_t k) {
    int lo = (int)(unsigned)k;
    int hi = (int)(unsigned)(k >> 32);
    int lo2 = __builtin_amdgcn_update_dpp(0, lo, CTRL, 0xF, 0xF, false);
    int hi2 = __builtin_amdgcn_update_dpp(0, hi, CTRL, 0xF, 0xF, false);
    uint64_t o = ((uint64_t)(unsigned)hi2 << 32) | (unsigned)lo2;
    return o > k ? o : k;
}

__device__ __forceinline__ uint64_t rdlane_u64(unsigned klo, unsigned khi, int l) {
    return ((uint64_t)(unsigned)__builtin_amdgcn_readlane((int)khi, l) << 32)
         |            (unsigned)__builtin_amdgcn_readlane((int)klo, l);
}

// ---------------------------------------------------------------------------
// FPS: one block per batch (256 threads). Bit-exact numpy (f32):
//   d = dx*dx + dy*dy + dz*dz (sequential adds, no FMA)
//   dist = min(dist,d); argmax first-index tie-break via packed u64
//   (dist_bits<<32)|~idx running max (16-deep, full ILP).
// Wave reduce: 4 DPP row stages -> rows hold row-max; readlane tree over
// lanes 0/16/32/48 (no DS op). Cross-wave via keylds; coords gathered from
// LDS-staged xyz. Centroids buffered in LDS, bulk-stored at end.
// ---------------------------------------------------------------------------
__global__ __launch_bounds__(256) void fps_kernel(
    const float* __restrict__ xyz,            // [B,N,3] f32
    float* __restrict__ out_xyz)              // d_out head [B,S,3] f32
{
#pragma clang fp contract(off)
    const int b    = blockIdx.x;
    const int tid  = threadIdx.x;
    const int lane = tid & 63;
    const int wave = tid >> 6;
    const float* xb = xyz + (size_t)b * NPTS * 3;

    __shared__ float xsh[NPTS], ysh[NPTS], zsh[NPTS];
    __shared__ float cents[NSAMP * 3];
    __shared__ uint64_t keylds[2][4];

    float px[16], py[16], pz[16], dist[16];
#pragma unroll
    for (int i = 0; i < 16; ++i) {
        int p = tid + (i << 8);
        px[i] = xb[p*3+0];
        py[i] = xb[p*3+1];
        pz[i] = xb[p*3+2];
        dist[i] = 1e10f;
        xsh[p] = px[i]; ysh[p] = py[i]; zsh[p] = pz[i];
    }
    __syncthreads();

    float cx = xb[0], cy = xb[1], cz = xb[2];

    for (int it = 0; it < NSAMP; ++it) {
        if (tid == 0) {                       // LDS only — no vmcnt traffic
            cents[it*3+0] = cx; cents[it*3+1] = cy; cents[it*3+2] = cz;
        }
        if (it == NSAMP - 1) break;

        // ---- local best over this thread's 16 points (ILP-rich) ----
        uint64_t k = 0;
#pragma unroll
        for (int i = 0; i < 16; ++i) {
            float dx = px[i] - cx, dy = py[i] - cy, dz = pz[i] - cz;
            float d = dx*dx; d = d + dy*dy; d = d + dz*dz;
            float nd = fminf(dist[i], d);
            dist[i] = nd;
            unsigned idx = (unsigned)(tid + (i << 8));
            uint64_t key = ((uint64_t)__float_as_uint(nd) << 32) | (~idx);
            k = key > k ? key : k;
        }

        // ---- wave reduce: 4 DPP row stages, then readlane tree ----
        k = dpp_max_u64<0x121>(k);   // row_ror:1
        k = dpp_max_u64<0x122>(k);   // row_ror:2
        k = dpp_max_u64<0x124>(k);   // row_ror:4
        k = dpp_max_u64<0x128>(k);   // row_ror:8  -> row(16) all-reduce
        unsigned klo = (unsigned)k, khi = (unsigned)(k >> 32);
        uint64_t r0 = rdlane_u64(klo, khi, 0);
        uint64_t r1 = rdlane_u64(klo, khi, 16);
        uint64_t r2 = rdlane_u64(klo, khi, 32);
        uint64_t r3 = rdlane_u64(klo, khi, 48);
        uint64_t ra = r0 > r1 ? r0 : r1;
        uint64_t rb = r2 > r3 ? r2 : r3;
        uint64_t wk = ra > rb ? ra : rb;

        // ---- cross-wave: 4 keys through LDS (double-buffered slot) ----
        int pb = it & 1;
        if (lane == 0) keylds[pb][wave] = wk;
        __syncthreads();                      // only lgkm pending — cheap
        uint64_t k0 = keylds[pb][0], k1 = keylds[pb][1];
        uint64_t k2 = keylds[pb][2], k3 = keylds[pb][3];
        uint64_t ka = k0 > k1 ? k0 : k1;
        uint64_t kb = k2 > k3 ? k2 : k3;
        uint64_t kf = ka > kb ? ka : kb;
        int cur = (int)~((unsigned)kf);

        cx = xsh[cur]; cy = ysh[cur]; cz = zsh[cur];
    }

    __syncthreads();
    for (int i = tid; i < NSAMP*3; i += 256)  // coalesced bulk store
        out_xyz[(size_t)b*NSAMP*3 + i] = cents[i];
}

// ---------------------------------------------------------------------------
// feat f32 -> bf16 table (one-shot; phases then stage with pure u16 copies)
// ---------------------------------------------------------------------------
__global__ __launch_bounds__(256) void conv_feat_kernel(
    const float* __restrict__ feat, unsigned short* __restrict__ featb)
{
    int t = blockIdx.x * 256 + threadIdx.x;   // 8 elems each; 4.19M total
    const float4* fp = (const float4*)feat + (size_t)t*2;
    float4 a = fp[0], c = fp[1];
    uint4 o;
    o.x = (unsigned)f2bf(a.x) | ((unsigned)f2bf(a.y) << 16);
    o.y = (unsigned)f2bf(a.z) | ((unsigned)f2bf(a.w) << 16);
    o.z = (unsigned)f2bf(c.x) | ((unsigned)f2bf(c.y) << 16);
    o.w = (unsigned)f2bf(c.z) | ((unsigned)f2bf(c.w) << 16);
    ((uint4*)featb)[t] = o;
}

// ---------------------------------------------------------------------------
// KNN: one wave per query. Filter-then-merge top-64 on packed u64
// (key<<32|idx) — exact lax.top_k semantics.
// ---------------------------------------------------------------------------
__global__ __launch_bounds__(256) void knn_kernel(
    const float* __restrict__ xyz,
    const float* __restrict__ new_xyz,        // Output 0 (f32)
    unsigned short* __restrict__ knn_idx)     // [B*S, 64]
{
#pragma clang fp contract(off)
    __shared__ float xs[NPTS], ys[NPTS], zs[NPTS];
    __shared__ uint64_t buf[4][64];
    const int tid  = threadIdx.x;
    const int lane = tid & 63;
    const int wave = tid >> 6;
    const int q = blockIdx.x * 4 + wave;
    const int b = q >> 10;
    const float* xb = xyz + (size_t)b * NPTS * 3;

    for (int i = tid; i < NPTS; i += 256) {
        xs[i] = xb[i*3+0];
        ys[i] = xb[i*3+1];
        zs[i] = xb[i*3+2];
    }
    __syncthreads();

    const float qx = new_xyz[q*3+0], qy = new_xyz[q*3+1], qz = new_xyz[q*3+2];
    float aa = qx*qx; aa = aa + qy*qy; aa = aa + qz*qz;

    auto keyof = [&](int c) -> unsigned {
        float x = xs[c], y = ys[c], z = zs[c];
        float bb = x*x;  bb = bb + y*y;   bb = bb + z*z;
        float dt = qx*x; dt = dt + qy*y;  dt = dt + qz*z;
        float d2 = (aa + bb) - 2.0f*dt;
        unsigned u = __float_as_uint(d2);
        return (u & 0x80000000u) ? ~u : (u | 0x80000000u);
    };
    auto shfl64 = [&](uint64_t v, int src) -> uint64_t {
        int lo = __shfl((int)(unsigned)v, src);
        int hi = __shfl((int)(unsigned)(v >> 32), src);
        return ((uint64_t)(unsigned)hi << 32) | (unsigned)lo;
    };
    auto shflx64 = [&](uint64_t v, int m) -> uint64_t {
        int lo = __shfl_xor((int)(unsigned)v, m);
        int hi = __shfl_xor((int)(unsigned)(v >> 32), m);
        return ((uint64_t)(unsigned)hi << 32) | (unsigned)lo;
    };
    auto sortP = [&](uint64_t &p) {        // ascending bitonic sort across 64
#pragma unroll
        for (int kk = 2; kk <= 64; kk <<= 1) {
#pragma unroll
            for (int j = kk >> 1; j >= 1; j >>= 1) {
                uint64_t o = shflx64(p, j);
                bool up    = ((lane & kk) == 0);
                bool lower = ((lane & j) == 0);
                bool oless = o < p;
                bool keep  = (up == lower) ? oless : !oless;
                if (keep) p = o;
            }
        }
    };
    auto mergeP = [&](uint64_t &P, uint64_t Bv) {  // both asc; keep 64 smallest
        uint64_t rev = shfl64(Bv, 63 - lane);
        if (rev < P) P = rev;                      // bitonic now
#pragma unroll
        for (int j = 32; j >= 1; j >>= 1) {
            uint64_t o = shflx64(P, j);
            bool lower = ((lane & j) == 0);
            bool oless = o < P;
            bool keep  = lower ? oless : !oless;
            if (keep) P = o;
        }
    };

    uint64_t P = ((uint64_t)keyof(lane) << 32) | (unsigned)lane;
    sortP(P);
    uint64_t Pmax = shfl64(P, 63);
    int cnt = 0;                                   // wave-uniform buffer fill

    for (int bt = 1; bt < 64; ++bt) {
        int c = (bt << 6) + lane;
        uint64_t cand = ((uint64_t)keyof(c) << 32) | (unsigned)c;
        bool qual = cand < Pmax;
        unsigned long long mask = __ballot(qual);
        if (mask == 0ull) continue;
        int n = __popcll(mask);
        if (cnt + n > 64) {                        // flush buffer
            uint64_t Bv = (lane < cnt) ? buf[wave][lane] : ~0ull;
            sortP(Bv);
            mergeP(P, Bv);
            Pmax = shfl64(P, 63);
            cnt = 0;
            qual = qual && (cand < Pmax);          // re-qualify (tightened)
            mask = __ballot(qual);
            n = __popcll(mask);
        }
        if (qual) {
            int pos = cnt + __popcll(mask & ((1ull << lane) - 1ull));
            buf[wave][pos] = cand;
        }
        cnt += n;
    }
    if (cnt > 0) {
        uint64_t Bv = (lane < cnt) ? buf[wave][lane] : ~0ull;
        sortP(Bv);
        mergeP(P, Bv);
    }
    knn_idx[(size_t)q*64 + lane] = (unsigned short)(P & 0xFFFFu);
}

// ---------------------------------------------------------------------------
// MLP phases — all 3 scales in one dispatch (3584 blocks, 8 groups/block).
// staged=1: feats come from pre-converted bf16 table (pure u16 copies).
// a_lds transpose slabs are WAVE-PRIVATE -> no barriers around the
// transpose round-trips.
// ---------------------------------------------------------------------------
#define GPB 8   // groups per block

template<int PHASE>
__global__ __launch_bounds__(256) void mlp_phase(
    const float* __restrict__ xyz,
    const float* __restrict__ feat,
    const float* __restrict__ w0,
    const float* __restrict__ w1,
    const float* __restrict__ w2,
    const float* __restrict__ new_xyz,    // Output 0 (f32)
    const unsigned short* __restrict__ knn,
    const unsigned short* __restrict__ featb,  // staged bf16 feats (or null)
    int staged,
    const float* __restrict__ bnp,        // [3][3][128][2] (s,t)
    float* __restrict__ stats,            // [3][3][128][2] (sum,sumsq)
    float* __restrict__ out1)             // fused region [B*S, 384] f32
{
    __shared__ __align__(16) unsigned short g_lds[64*104];
    __shared__ __align__(16) unsigned short a_lds[64*72];
    __shared__ float stat_lds[256];
    __shared__ float wavemax[4*128];

    const int tid  = threadIdx.x;
    const int lane = tid & 63;
    const int wave = tid >> 6;
    const int n16  = lane & 15;
    const int quad = lane >> 4;

    int scale, g0;
    {
        int blk = blockIdx.x;
        if (blk < 512)       { scale = 0; g0 = blk * GPB; }
        else if (blk < 1536) { scale = 1; g0 = (blk - 512) * GPB; }
        else                 { scale = 2; g0 = (blk - 1536) * GPB; }
    }
    const int KNB = 16 << scale;
    const int cpg = 4 >> scale;           // centroids per 64-row group
    const int wpc = 1 << scale;           // waves per centroid

    // ---- W fragments (B-operand layout: n=lane&15, k=quad*8+j) ----
    short8 w1f[4][3];
#pragma unroll
    for (int nt = 0; nt < 4; ++nt)
#pragma unroll
        for (int kb = 0; kb < 3; ++kb) {
            short8 f;
#pragma unroll
            for (int j = 0; j < 8; ++j) {
                int kg = kb*32 + quad*8 + j;
                int n  = nt*16 + n16;
                unsigned short v = 0;
                if (kg < 67) {
                    int ci = (kg < 64) ? (kg + 3) : (kg - 64);
                    v = f2bf(w0[(size_t)(scale*64 + n)*67 + ci]);
                }
                f[j] = (short)v;
            }
            w1f[nt][kb] = f;
        }
    short8 w2f[4][2];
    if constexpr (PHASE >= 2) {
#pragma unroll
        for (int nt = 0; nt < 4; ++nt)
#pragma unroll
            for (int kb = 0; kb < 2; ++kb) {
                short8 f;
#pragma unroll
                for (int j = 0; j < 8; ++j) {
                    int kg = kb*32 + quad*8 + j;
                    int n  = nt*16 + n16;
                    f[j] = (short)f2bf(w1[(size_t)(scale*64 + n)*64 + kg]);
                }
                w2f[nt][kb] = f;
            }
    }
    short8 w3f[8][2];
    if constexpr (PHASE >= 3) {
#pragma unroll
        for (int nt = 0; nt < 8; ++nt)
#pragma unroll
            for (int kb = 0; kb < 2; ++kb) {
                short8 f;
#pragma unroll
                for (int j = 0; j < 8; ++j) {
                    int kg = kb*32 + quad*8 + j;
                    int n  = nt*16 + n16;
                    f[j] = (short)f2bf(w2[(size_t)(scale*128 + n)*64 + kg]);
                }
                w3f[nt][kb] = f;
            }
    }

    float s1p[4], t1p[4], s2p[4], t2p[4];
    if constexpr (PHASE >= 2) {
#pragma unroll
        for (int nt = 0; nt < 4; ++nt) {
            int o = ((0*3 + scale)*128 + nt*16 + n16)*2;
            s1p[nt] = bnp[o]; t1p[nt] = bnp[o+1];
        }
    }
    if constexpr (PHASE >= 3) {
#pragma unroll
        for (int nt = 0; nt < 4; ++nt) {
            int o = ((1*3 + scale)*128 + nt*16 + n16)*2;
            s2p[nt] = bnp[o]; t2p[nt] = bnp[o+1];
        }
    }

    float sac[8], sqac[8];
#pragma unroll
    for (int i = 0; i < 8; ++i) { sac[i] = 0.f; sqac[i] = 0.f; }
    stat_lds[tid] = 0.f;
    __syncthreads();

    for (int g = g0; g < g0 + GPB; ++g) {
        const int cb = g * cpg;
        // ---- build g tile: 64 rows x 104 cols (bf16) ----
        {
            const int r   = tid >> 2;
            const int sub = tid & 3;
            const int ci  = cb + (r >> (4 + scale));
            const int j   = r & (KNB - 1);
            const int n   = knn[(size_t)ci*64 + j];
            const int b   = ci >> 10;
            if (staged) {
                const unsigned short* frow = featb + ((size_t)(b*NPTS + n))*64 + sub*16;
                uint4 c0 = ((const uint4*)frow)[0];
                uint4 c1 = ((const uint4*)frow)[1];
                *(uint4*)&g_lds[r*104 + sub*16]     = c0;
                *(uint4*)&g_lds[r*104 + sub*16 + 8] = c1;
            } else {
                const float* frow = feat + ((size_t)(b*NPTS + n))*64 + sub*16;
                unsigned short h[16];
#pragma unroll
                for (int u = 0; u < 16; ++u) h[u] = f2bf(frow[u]);
                uint4 p0, p1;
                p0.x = (unsigned)h[0]  | ((unsigned)h[1]  << 16);
                p0.y = (unsigned)h[2]  | ((unsigned)h[3]  << 16);
                p0.z = (unsigned)h[4]  | ((unsigned)h[5]  << 16);
                p0.w = (unsigned)h[6]  | ((unsigned)h[7]  << 16);
                p1.x = (unsigned)h[8]  | ((unsigned)h[9]  << 16);
                p1.y = (unsigned)h[10] | ((unsigned)h[11] << 16);
                p1.z = (unsigned)h[12] | ((unsigned)h[13] << 16);
                p1.w = (unsigned)h[14] | ((unsigned)h[15] << 16);
                *(uint4*)&g_lds[r*104 + sub*16]     = p0;
                *(uint4*)&g_lds[r*104 + sub*16 + 8] = p1;
            }
            if (sub == 0) {
                const float* nx = new_xyz + (size_t)ci*3;
                const float* xp = xyz + ((size_t)(b*NPTS + n))*3;
                unsigned short h0 = f2bf(xp[0] - nx[0]);
                unsigned short h1 = f2bf(xp[1] - nx[1]);
                unsigned short h2 = f2bf(xp[2] - nx[2]);
                uint4 z = make_uint4((unsigned)h0 | ((unsigned)h1 << 16),
                                     (unsigned)h2, 0u, 0u);
                *(uint4*)&g_lds[r*104 + 64] = z;
                *(uint4*)&g_lds[r*104 + 72] = make_uint4(0u,0u,0u,0u);
            } else if (sub == 1) {
                *(uint4*)&g_lds[r*104 + 80] = make_uint4(0u,0u,0u,0u);
            } else if (sub == 2) {
                *(uint4*)&g_lds[r*104 + 88] = make_uint4(0u,0u,0u,0u);
            }
        }
        __syncthreads();

        // ---- L1 ----
        const int rb = wave*16 + n16;  // A-row for this lane
        short8 a0 = *(const short8*)&g_lds[rb*104 +      quad*8];
        short8 a1 = *(const short8*)&g_lds[rb*104 + 32 + quad*8];
        short8 a2 = *(const short8*)&g_lds[rb*104 + 64 + quad*8];
        floatx4 acc[4];
#pragma unroll
        for (int nt = 0; nt < 4; ++nt) {
            floatx4 c = {0.f,0.f,0.f,0.f};
            c = __builtin_amdgcn_mfma_f32_16x16x32_bf16(a0, w1f[nt][0], c, 0,0,0);
            c = __builtin_amdgcn_mfma_f32_16x16x32_bf16(a1, w1f[nt][1], c, 0,0,0);
            c = __builtin_amdgcn_mfma_f32_16x16x32_bf16(a2, w1f[nt][2], c, 0,0,0);
            acc[nt] = c;
        }

        if constexpr (PHASE == 1) {
#pragma unroll
            for (int nt = 0; nt < 4; ++nt) {
                floatx4 c = acc[nt];
                sac[nt]  += c[0]+c[1]+c[2]+c[3];
                sqac[nt] += c[0]*c[0]+c[1]*c[1]+c[2]*c[2]+c[3]*c[3];
            }
        }
        if constexpr (PHASE >= 2) {
            // a1 = relu(affine(x1)) -> LDS transpose (wave-private slab)
#pragma unroll
            for (int nt = 0; nt < 4; ++nt) {
                int ch = nt*16 + n16;
#pragma unroll
                for (int r = 0; r < 4; ++r) {
                    float v = acc[nt][r]*s1p[nt] + t1p[nt];
                    v = fmaxf(v, 0.f);
                    a_lds[(wave*16 + quad*4 + r)*72 + ch] = f2bf(v);
                }
            }
            short8 e0 = *(const short8*)&a_lds[rb*72 +      quad*8];
            short8 e1 = *(const short8*)&a_lds[rb*72 + 32 + quad*8];
            floatx4 acc2[4];
#pragma unroll
            for (int nt = 0; nt < 4; ++nt) {
                floatx4 c = {0.f,0.f,0.f,0.f};
                c = __builtin_amdgcn_mfma_f32_16x16x32_bf16(e0, w2f[nt][0], c, 0,0,0);
                c = __builtin_amdgcn_mfma_f32_16x16x32_bf16(e1, w2f[nt][1], c, 0,0,0);
                acc2[nt] = c;
            }
            if constexpr (PHASE == 2) {
#pragma unroll
                for (int nt = 0; nt < 4; ++nt) {
                    floatx4 c = acc2[nt];
                    sac[nt]  += c[0]+c[1]+c[2]+c[3];
                    sqac[nt] += c[0]*c[0]+c[1]*c[1]+c[2]*c[2]+c[3]*c[3];
                }
            }
            if constexpr (PHASE == 3) {
#pragma unroll
                for (int nt = 0; nt < 4; ++nt) {
                    int ch = nt*16 + n16;
#pragma unroll
                    for (int r = 0; r < 4; ++r) {
                        float v = acc2[nt][r]*s2p[nt] + t2p[nt];
                        v = fmaxf(v, 0.f);
                        a_lds[(wave*16 + quad*4 + r)*72 + ch] = f2bf(v);
                    }
                }
                short8 f0 = *(const short8*)&a_lds[rb*72 +      quad*8];
                short8 f1 = *(const short8*)&a_lds[rb*72 + 32 + quad*8];
                floatx4 acc3[8];
#pragma unroll
                for (int nt = 0; nt < 8; ++nt) {
                    floatx4 c = {0.f,0.f,0.f,0.f};
                    c = __builtin_amdgcn_mfma_f32_16x16x32_bf16(f0, w3f[nt][0], c, 0,0,0);
                    c = __builtin_amdgcn_mfma_f32_16x16x32_bf16(f1, w3f[nt][1], c, 0,0,0);
                    acc3[nt] = c;
                }
#pragma unroll
                for (int nt = 0; nt < 8; ++nt) {
                    floatx4 c = acc3[nt];
                    sac[nt]  += c[0]+c[1]+c[2]+c[3];
                    sqac[nt] += c[0]*c[0]+c[1]*c[1]+c[2]*c[2]+c[3]*c[3];
                    float m = fmaxf(fmaxf(c[0],c[1]), fmaxf(c[2],c[3]));
                    m = fmaxf(m, __shfl_xor(m, 16));
                    m = fmaxf(m, __shfl_xor(m, 32));
                    if (lane < 16) wavemax[wave*128 + nt*16 + n16] = m;
                }
            }
        }
        __syncthreads();   // g_lds reuse (all) + cross-wave wavemax (PHASE 3)
        if constexpr (PHASE == 3) {
            const int ch = tid & 127;
            for (int ic = tid >> 7; ic < cpg; ic += 2) {
                float m = wavemax[(ic*wpc)*128 + ch];
                for (int w = 1; w < wpc; ++w)
                    m = fmaxf(m, wavemax[(ic*wpc + w)*128 + ch]);
                // raw (pre-BN3) max, f32, directly in the final output slot
                out1[(size_t)(cb + ic)*384 + scale*128 + ch] = m;
            }
        }
    }

    // ---- flush stats ----
    const int NCH = (PHASE == 3) ? 8 : 4;
#pragma unroll
    for (int nt = 0; nt < 8; ++nt) {
        if (nt >= NCH) break;
        float v  = sac[nt], v2 = sqac[nt];
        v  += __shfl_xor(v, 16);  v  += __shfl_xor(v, 32);
        v2 += __shfl_xor(v2, 16); v2 += __shfl_xor(v2, 32);
        if (lane < 16) {
            int ch = nt*16 + n16;
            atomicAdd(&stat_lds[ch*2],   v);
            atomicAdd(&stat_lds[ch*2+1], v2);
        }
    }
    __syncthreads();
    const int layer = PHASE - 1;
    const int nch = (PHASE == 3) ? 128 : 64;
    if (tid < nch*2) {
        atomicAdd(&stats[(size_t)(layer*3 + scale)*256 + tid], stat_lds[tid]);
    }
}

// ---------------------------------------------------------------------------
__global__ void bn_params_kernel(
    const float* __restrict__ stats, float* __restrict__ bnp,
    const float* __restrict__ gamma, const float* __restrict__ beta,
    int layer, int nch)
{
    int t = blockIdx.x * blockDim.x + threadIdx.x;
    if (t >= 3*nch) return;
    int scale = t / nch, ch = t % nch;
    float M = 16384.0f * (float)(16 << scale);
    int o = ((layer*3 + scale)*128 + ch)*2;
    float sum = stats[o], sumsq = stats[o+1];
    float mean = sum / M;
    float var = sumsq / M - mean*mean;
    var = fmaxf(var, 0.f);
    float ga = gamma[scale*nch + ch];
    float be = beta[scale*nch + ch];
    float s  = ga / sqrtf(var + 1e-5f);
    float tt = be - mean * s;
    bnp[o] = s; bnp[o+1] = tt;
}

// In-place elementwise BN3+ReLU over the fused output region (f32).
__global__ void finalize_kernel(
    const float* __restrict__ bnp,
    float* __restrict__ out1)   // [B*S, 384] f32, holds raw maxima
{
    int t = blockIdx.x * 256 + threadIdx.x;    // flat over 16384*384
    int q = t / 384;
    int c = t - q*384;
    int scale = c >> 7;
    int ch = c & 127;
    float m = out1[t];
    int o = ((2*3 + scale)*128 + ch)*2;
    float v = m * bnp[o] + bnp[o+1];
    v = fmaxf(v, 0.f);
    out1[t] = v;
}

// ---------------------------------------------------------------------------
extern "C" void kernel_launch(void* const* d_in, const int* in_sizes, int n_in,
                              void* d_out, int out_size, void* d_ws, size_t ws_size,
                              hipStream_t stream)
{
    (void)in_sizes; (void)n_in; (void)out_size;
    const float* xyz  = (const float*)d_in[0];
    const float* feat = (const float*)d_in[1];
    const float* w0   = (const float*)d_in[2];
    const float* w1   = (const float*)d_in[3];
    const float* w2   = (const float*)d_in[4];
    const float* g0   = (const float*)d_in[5];
    const float* g1   = (const float*)d_in[6];
    const float* g2   = (const float*)d_in[7];
    const float* b0   = (const float*)d_in[8];
    const float* b1   = (const float*)d_in[9];
    const float* b2   = (const float*)d_in[10];
    float* out  = (float*)d_out;
    float* out0 = out;                 // [B,S,3]
    float* out1 = out + 49152;         // fused [B*S,384]

    // ws layout: knn 2MB | featb 8MB | stats | bnp   (staged, NEED=10.5MB)
    //            knn 2MB | stats | bnp                (fallback)
    char* ws = (char*)d_ws;
    const size_t NEED = 2097152ull + 8388608ull + 9216ull + 9216ull;
    const int staged = (ws_size >= NEED) ? 1 : 0;
    unsigned short* knn   = (unsigned short*)(ws + 0);
    unsigned short* featb = staged ? (unsigned short*)(ws + 2097152) : nullptr;
    float* stats = (float*)(ws + (staged ? 10485760u : 2097152u));
    float* bnp   = stats + 2304;

    hipMemsetAsync(stats, 0, 9216, stream);
    fps_kernel<<<16, 256, 0, stream>>>(xyz, out0);
    if (staged) conv_feat_kernel<<<2048, 256, 0, stream>>>(feat, featb);
    knn_kernel<<<4096, 256, 0, stream>>>(xyz, out0, knn);

    mlp_phase<1><<<3584,256,0,stream>>>(xyz,feat,w0,w1,w2,out0,knn,featb,staged,bnp,stats,out1);
    bn_params_kernel<<<1,256,0,stream>>>(stats, bnp, g0, b0, 0, 64);

    mlp_phase<2><<<3584,256,0,stream>>>(xyz,feat,w0,w1,w2,out0,knn,featb,staged,bnp,stats,out1);
    bn_params_kernel<<<1,256,0,stream>>>(stats, bnp, g1, b1, 1, 64);

    mlp_phase<3><<<3584,256,0,stream>>>(xyz,feat,w0,w1,w2,out0,knn,featb,staged,bnp,stats,out1);
    bn_params_kernel<<<2,256,0,stream>>>(stats, bnp, g2, b2, 2, 128);

    finalize_kernel<<<24576, 256, 0, stream>>>(bnp, out1);
}